// Round 16
// baseline (28.866 us; speedup 1.0000x reference)
//
#include <hip/hip_runtime.h>

// CGP coupler, single/duo/quad packed, b128 8-row geometry.
//
// Structure (validated R3-R15): runs of 32 entries = segments
//   out[:, 32*ob:32*ob+32] += cg * x1[:, a:a+32] * x2[:, b:b+32]
// nseg ~ 580, nob = 280, per-ob counts c in 0..7 (avg ~2), a,b 32-aligned.
//
// R15 -> R16: pad-slot elimination. Classes by per-ob segment count c:
//   c<=1 -> single (1 slot; c==0 is a cg=0 pad that stores the needed zeros)
//   c==2 -> duo    (2 slots, zero pads)
//   3<=c<=4 -> quad (4 slots, exclusive store)
//   c>=5 -> quads  (shared: pre-zeroed, global native fadd)
// Slots drop ~900 -> ~650 (-25-30% ds_read_b128 traffic). Prep scans all
// four class counters in ONE 64-bit packed wave-shuffle scan (16b fields).

#define IN_DIM  1024
#define ROWS    8
#define NOBCAP  512
#define SKIP_OB 511u

// ---- prep (1 block, 1024 thr): count -> packed u64 shuffle scan -> fill ----
__global__ __launch_bounds__(1024) void prep_kernel(
    const int* __restrict__ r1, const int* __restrict__ r2,
    const int* __restrict__ ro, const float* __restrict__ cg,
    int nseg, int nob,
    uint2* __restrict__ qdesc, uint2* __restrict__ ddesc, uint2* __restrict__ sdesc,
    int* __restrict__ zlist, int* __restrict__ hdr)
{
    __shared__ int cntS[NOBCAP], rankS[NOBCAP];
    __shared__ int qoffS[NOBCAP], doffS[NOBCAP], soffS[NOBCAP];
    __shared__ unsigned long long wsumS[8], woffS[8];
    const int t = threadIdx.x;

    if (t < NOBCAP) { cntS[t] = 0; rankS[t] = 0; }
    __syncthreads();

    for (int s = t; s < nseg; s += 1024)
        atomicAdd(&cntS[ro[s << 5] >> 5], 1);
    __syncthreads();

    // packed per-ob: q<<48 | duo<<32 | single<<16 | shared ; totals << 65536
    int c = 0;
    unsigned long long pv = 0ull;
    if (t < NOBCAP) {
        c = (t < nob) ? cntS[t] : 0;
        unsigned long long q = 0, df = 0, sf = 0, zf = 0;
        if (t < nob) {
            if (c == 2)      df = 1;
            else if (c <= 1) sf = 1;
            else { q = (unsigned long long)((c + 3) >> 2); if (c > 4) zf = 1; }
        }
        pv = (q << 48) | (df << 32) | (sf << 16) | zf;
    }
    const int lane = t & 63;
    const int wid  = t >> 6;
    #pragma unroll
    for (int off = 1; off < 64; off <<= 1) {
        const unsigned long long n = __shfl_up(pv, off, 64);
        if (lane >= off) pv += n;
    }
    if (t < NOBCAP && lane == 63) wsumS[wid] = pv;
    __syncthreads();
    if (t < 8) {
        unsigned long long v = wsumS[t];
        const unsigned long long self = v;
        #pragma unroll
        for (int off = 1; off < 8; off <<= 1) {
            const unsigned long long n = __shfl_up(v, off, 64);
            if (t >= off) v += n;
        }
        woffS[t] = v - self;                 // exclusive wave offset
    }
    __syncthreads();

    if (t < NOBCAP) {
        const unsigned long long incl = pv + woffS[wid];
        const int qi = (int)(incl >> 48);
        const int di = (int)((incl >> 32) & 0xFFFFull);
        const int si = (int)((incl >> 16) & 0xFFFFull);
        const int zi = (int)(incl & 0xFFFFull);
        if (t < nob) {
            if (c == 2) {
                doffS[t] = di - 1;
            } else if (c <= 1) {
                soffS[t] = si - 1;
                if (c == 0)                  // empty ob: store zeros via pad
                    sdesc[si - 1] = make_uint2(((unsigned int)t << 20) | 0x80000000u, 0u);
            } else {
                const int qn = (c + 3) >> 2;
                const int qb = qi - qn;
                qoffS[t] = qb;
                const unsigned int fl = (c > 4) ? 0u : 0x80000000u;
                if (c > 4) zlist[zi - 1] = t;
                const unsigned int pd = ((unsigned int)t << 20) | fl;
                for (int j = (qb << 2) + c; j < ((qb + qn) << 2); ++j)
                    qdesc[j] = make_uint2(pd, 0u);
            }
        }
        if (t == NOBCAP - 1) {
            const int nq = qi, nd = di, ns = si;
            const int nqPad = (nq + 15) & ~15;   // 16 quads  (1/wave)
            const int ndPad = (nd + 31) & ~31;   // 32 duos   (1 pair/wave)
            const int nsPad = (ns + 63) & ~63;   // 64 singles(4/wave-iter)
            const uint2 dummy = make_uint2(SKIP_OB << 20, 0u);
            for (int j = (nq << 2); j < (nqPad << 2); ++j) qdesc[j] = dummy;
            for (int j = (nd << 1); j < (ndPad << 1); ++j) ddesc[j] = dummy;
            for (int j = ns;        j < nsPad;        ++j) sdesc[j] = dummy;
            hdr[0] = nqPad; hdr[1] = zi; hdr[2] = ndPad; hdr[3] = nsPad;
        }
    }
    __syncthreads();

    for (int s = t; s < nseg; s += 1024) {
        const int k  = s << 5;
        const int ob = ro[k] >> 5;
        const int cc = cntS[ob];
        const int rk = atomicAdd(&rankS[ob], 1);
        const unsigned int fl = (cc > 4) ? 0u : 0x80000000u;
        const uint2 v = make_uint2((unsigned int)r1[k] | ((unsigned int)r2[k] << 10)
                                   | ((unsigned int)ob << 20) | fl,
                                   __float_as_uint(cg[k]));
        if (cc == 2)      ddesc[(doffS[ob] << 1) + rk] = v;
        else if (cc == 1) sdesc[soffS[ob]] = v;
        else              qdesc[(qoffS[ob] << 2) + rk] = v;
    }
}

__device__ __forceinline__ void accum4(float4& acc, unsigned int dx, unsigned int dc,
                                       const float* xs1, const float* xs2)
{
    const float  c = __uint_as_float(dc);
    const float4 u = *reinterpret_cast<const float4*>(xs1 + (dx & 1023u));
    const float4 v = *reinterpret_cast<const float4*>(xs2 + ((dx >> 10) & 1023u));
    acc.x = fmaf(c, u.x * v.x, acc.x);
    acc.y = fmaf(c, u.y * v.y, acc.y);
    acc.z = fmaf(c, u.z * v.z, acc.z);
    acc.w = fmaf(c, u.w * v.w, acc.w);
}

__device__ __forceinline__ void terminal(float* orow, unsigned int hx, float4 acc)
{
    const int ob = (int)((hx >> 20) & 511u);
    if (ob == (int)SKIP_OB) return;                  // tail pad: no output
    float* p = orow + (ob << 5);
    if (hx >> 31) {
        *reinterpret_cast<float4*>(p) = acc;         // exclusive: plain store
    } else {                                         // shared: native fadd
        unsafeAtomicAdd(p,     acc.x);
        unsafeAtomicAdd(p + 1, acc.y);
        unsafeAtomicAdd(p + 2, acc.z);
        unsafeAtomicAdd(p + 3, acc.w);
    }
}

// ---- main: block = 8 rows, 16 waves; lane = row(3b) x float4-group(3b) ----
__global__ __launch_bounds__(1024) void cgp_main(const float* __restrict__ x1,
    const float* __restrict__ x2, const uint2* __restrict__ qdesc,
    const uint2* __restrict__ ddesc, const uint2* __restrict__ sdesc,
    const int* __restrict__ zlist, const int* __restrict__ hdr,
    float* __restrict__ out, int out_dim)
{
    __shared__ float x1s[ROWS * IN_DIM];             // 32 KB
    __shared__ float x2s[ROWS * IN_DIM];             // 32 KB
    const int r0  = blockIdx.x * ROWS;
    const int tid = threadIdx.x;

    {
        const float4* p1 = reinterpret_cast<const float4*>(x1 + (size_t)r0 * IN_DIM);
        const float4* p2 = reinterpret_cast<const float4*>(x2 + (size_t)r0 * IN_DIM);
        float4* s1 = reinterpret_cast<float4*>(x1s);
        float4* s2 = reinterpret_cast<float4*>(x2s);
        #pragma unroll
        for (int j = tid; j < (ROWS * IN_DIM) >> 2; j += 1024) { s1[j] = p1[j]; s2[j] = p2[j]; }
    }
    const int nz = hdr[1];
    for (int i = tid; i < (nz << 5); i += 1024) {    // pre-zero shared obs
        const int ob = zlist[i >> 5];
        const int ch = i & 31;
        float* p = out + (size_t)r0 * out_dim + (ob << 5) + ch;
        #pragma unroll
        for (int j = 0; j < ROWS; ++j) p[j * out_dim] = 0.f;
    }
    __syncthreads();

    const int w  = tid >> 6;                         // wave 0..15
    const int ln = tid & 63;
    const int rr = ln >> 3;                          // row 0..7
    const int tt = ln & 7;                           // float4-channel group
    const float* xs1 = x1s + rr * IN_DIM + (tt << 2);
    const float* xs2 = x2s + rr * IN_DIM + (tt << 2);
    float* orow = out + (size_t)(r0 + rr) * out_dim + (tt << 2);

    // ---- quad loop (obs with c>=3) ----
    {
        const int qpw = hdr[0] >> 4;
        const uint2* qd = qdesc + ((size_t)(w * qpw) << 2);
        #pragma unroll 2
        for (int i = 0; i < qpw; ++i, qd += 4) {
            const uint4 A  = *reinterpret_cast<const uint4*>(qd);
            const uint4 Bq = *reinterpret_cast<const uint4*>(qd + 2);
            float4 acc = make_float4(0.f, 0.f, 0.f, 0.f);
            accum4(acc, A.x,  A.y,  xs1, xs2);
            accum4(acc, A.z,  A.w,  xs1, xs2);
            accum4(acc, Bq.x, Bq.y, xs1, xs2);
            accum4(acc, Bq.z, Bq.w, xs1, xs2);
            terminal(orow, A.x, acc);
        }
    }

    // ---- duo-pair loop (obs with c==2) ----
    {
        const int ppw = hdr[2] >> 5;                 // duo-pairs per wave
        const uint2* dd = ddesc + ((size_t)(w * ppw) << 2);
        #pragma unroll 2
        for (int i = 0; i < ppw; ++i, dd += 4) {
            const uint4 A  = *reinterpret_cast<const uint4*>(dd);
            const uint4 Bq = *reinterpret_cast<const uint4*>(dd + 2);
            float4 a0 = make_float4(0.f, 0.f, 0.f, 0.f);
            float4 a1 = make_float4(0.f, 0.f, 0.f, 0.f);
            accum4(a0, A.x,  A.y,  xs1, xs2);
            accum4(a0, A.z,  A.w,  xs1, xs2);
            accum4(a1, Bq.x, Bq.y, xs1, xs2);
            accum4(a1, Bq.z, Bq.w, xs1, xs2);
            terminal(orow, A.x,  a0);
            terminal(orow, Bq.x, a1);
        }
    }

    // ---- singles loop (obs with c<=1; 4 independent descs per iter) ----
    {
        const int spw = hdr[3] >> 4;                 // singles per wave (mult of 4)
        const int ipw = spw >> 2;                    // iterations (4 singles each)
        const uint2* sd = sdesc + (size_t)(w * spw);
        #pragma unroll 2
        for (int i = 0; i < ipw; ++i, sd += 4) {
            const uint4 A  = *reinterpret_cast<const uint4*>(sd);
            const uint4 Bq = *reinterpret_cast<const uint4*>(sd + 2);
            float4 a0 = make_float4(0.f, 0.f, 0.f, 0.f);
            float4 a1 = make_float4(0.f, 0.f, 0.f, 0.f);
            float4 a2 = make_float4(0.f, 0.f, 0.f, 0.f);
            float4 a3 = make_float4(0.f, 0.f, 0.f, 0.f);
            accum4(a0, A.x,  A.y,  xs1, xs2);
            accum4(a1, A.z,  A.w,  xs1, xs2);
            accum4(a2, Bq.x, Bq.y, xs1, xs2);
            accum4(a3, Bq.z, Bq.w, xs1, xs2);
            terminal(orow, A.x,  a0);
            terminal(orow, A.z,  a1);
            terminal(orow, Bq.x, a2);
            terminal(orow, Bq.z, a3);
        }
    }
}

extern "C" void kernel_launch(void* const* d_in, const int* in_sizes, int n_in,
                              void* d_out, int out_size, void* d_ws, size_t ws_size,
                              hipStream_t stream)
{
    const float* x1 = (const float*)d_in[0];
    const float* x2 = (const float*)d_in[1];
    const float* cg = (const float*)d_in[2];
    const int*   r1 = (const int*)d_in[3];
    const int*   r2 = (const int*)d_in[4];
    const int*   ro = (const int*)d_in[5];
    float* out = (float*)d_out;

    const int B       = in_sizes[0] / IN_DIM;   // 2048
    const int out_dim = out_size / B;           // 8960
    const int K       = in_sizes[2];
    const int nseg    = K >> 5;                 // ~580
    const int nob     = out_dim >> 5;           // 280
    const int qcap    = nob + (nseg >> 2) + 32; // quad capacity (slots/4)
    const int dcap    = nob + 48;               // duo capacity (slots/2)
    const int scap    = nob + 80;               // single capacity (slots)

    auto align16 = [](size_t v) { return (v + 15) & ~(size_t)15; };
    char* ws = (char*)d_ws;
    uint2* qdesc = (uint2*)ws;  ws += align16((size_t)qcap * 4 * sizeof(uint2));
    uint2* ddesc = (uint2*)ws;  ws += align16((size_t)dcap * 2 * sizeof(uint2));
    uint2* sdesc = (uint2*)ws;  ws += align16((size_t)scap * sizeof(uint2));
    int*   zlist = (int*)ws;    ws += align16((size_t)NOBCAP * sizeof(int));
    int*   hdr   = (int*)ws;

    hipLaunchKernelGGL(prep_kernel, dim3(1), dim3(1024), 0, stream,
                       r1, r2, ro, cg, nseg, nob, qdesc, ddesc, sdesc, zlist, hdr);
    hipLaunchKernelGGL(cgp_main, dim3(B / ROWS), dim3(1024), 0, stream,
                       x1, x2, qdesc, ddesc, sdesc, zlist, hdr, out, out_dim);
}